// Round 4
// baseline (687.593 us; speedup 1.0000x reference)
//
#include <hip/hip_runtime.h>

// Problem constants (fixed by the reference setup_inputs).
#define VSZ 50000   // vocab
#define ESZ 100     // embedding dim
#define HSZ 64      // hidden
#define GSZ 256     // 4*H (gate width, PyTorch order i,f,g,o)
#define BSZ 256     // batch
#define TSZ 512     // seq len

__device__ __forceinline__ float fast_rcp(float x) { return __builtin_amdgcn_rcpf(x); }
__device__ __forceinline__ float sigmoid_f(float x) { return fast_rcp(1.f + __expf(-x)); }
__device__ __forceinline__ float tanh_f(float x) {
    float e = __expf(2.f * x);
    return 1.f - 2.f * fast_rcp(e + 1.f);
}

// ---------------------------------------------------------------------------
// Kernel A: G[v, col] = sum_e emb[v,e]*w_ih0[row,e] + b_ih0[row] + b_hh0[row],
// PERMUTED col = 4*(row%64) + row/64 so the recurrent kernel's lane (q,j)
// reads its gate scalar at col 4q+j. Per-lane w_ih0 row in VGPRs; emb rows
// read as block-uniform BROADCAST vector loads (pointer laundered through a
// VGPR so uniformity analysis cannot scalarize them into capacity-limited
// s_loads -- the round-3 build_table bottleneck).
// ---------------------------------------------------------------------------
__global__ __launch_bounds__(256, 2) void build_table(
    const float* __restrict__ emb, const float* __restrict__ w_ih0,
    const float* __restrict__ b_ih0, const float* __restrict__ b_hh0,
    float* __restrict__ Gt)
{
    const int g = threadIdx.x;            // PyTorch gate-row index 0..255
    const int row0 = blockIdx.x * 32;
    const int col = ((g & 63) << 2) + (g >> 6);   // permuted column

    float w[ESZ];
    #pragma unroll
    for (int e = 0; e < ESZ; e += 4) {
        float4 v = *(const float4*)(w_ih0 + g * ESZ + e);
        w[e] = v.x; w[e + 1] = v.y; w[e + 2] = v.z; w[e + 3] = v.w;
    }
    const float bias = b_ih0[g] + b_hh0[g];

    #pragma unroll 1
    for (int r = row0; r < row0 + 32; r += 2) {
        if (r + 1 >= VSZ + 1) break;      // VSZ even: pairs complete
        if (r >= VSZ) break;
        unsigned long long u0 = (unsigned long long)(emb + (size_t)r * ESZ);
        asm("" : "+v"(u0));               // force per-lane (vector) load path
        const float* e0 = (const float*)u0;
        const float* e1 = e0 + ESZ;
        float a0 = bias, a1 = 0.f, a2 = 0.f, a3 = 0.f;
        float b0 = bias, b1 = 0.f, b2 = 0.f, b3 = 0.f;
        #pragma unroll
        for (int e = 0; e < ESZ; e += 4) {
            float4 u = *(const float4*)(e0 + e);
            float4 v = *(const float4*)(e1 + e);
            a0 += u.x * w[e]; a1 += u.y * w[e + 1];
            a2 += u.z * w[e + 2]; a3 += u.w * w[e + 3];
            b0 += v.x * w[e]; b1 += v.y * w[e + 1];
            b2 += v.z * w[e + 2]; b3 += v.w * w[e + 3];
        }
        Gt[(size_t)r       * GSZ + col] = (a0 + a1) + (a2 + a3);
        Gt[(size_t)(r + 1) * GSZ + col] = (b0 + b1) + (b2 + b3);
    }
}

// ---------------------------------------------------------------------------
// Kernel B: fused 2-layer LSTM + FC head, 1 block (768 thr) per batch row.
//
// Group A (tid<256): layer 0. unit q = tid>>2, slice j = tid&3 (16 h-vals).
//   Weights: w_hh0 rows {q,64+q,128+q,192+q}, cols [16j,16j+16) = 16 float4.
// Group B (tid>=256): layer 1. lt=tid-256, q=lt>>3, j=lt&7 (8 h-vals).
//   Weights: w_ih1 (2 f4) ++ w_hh1 (2 f4) per gate = 16 float4; the H
//   operand is h0-slice ++ h1-slice, so the dot code is IDENTICAL to A's.
// 64 weight floats/thread, loaded ONCE and laundered through asm (cannot be
// rematerialized); NO per-iteration pins (round-3's AGPR ping-pong bug).
//
// Per step: 64 FMA -> reduce-scatter (B: +4 xor4 shuffles; both: xor2 pair,
// xor1) so lane j&3 holds gate j&3's dot -> ONE activation per lane via
// act = fma(Bc, rcp(1+exp(mc*s)), Ac) -> 3-shuffle allgather -> c,h update
// replicated in the quad, lane j==0 publishes h to LDS.
//
// Software pipeline: A computes layer-0 step k while B computes layer-1 step
// k-1; ONE lgkm-only barrier per step (Gt prefetch stays in flight).
// ---------------------------------------------------------------------------
__device__ __forceinline__ void sync_lds() {
    asm volatile("s_waitcnt lgkmcnt(0)\n\ts_barrier" ::: "memory");
}

#define LD4(ptr, off) (*(const float4*)((ptr) + (off)))
#define PIN4(v) asm("" : "+v"(v.x), "+v"(v.y), "+v"(v.z), "+v"(v.w))
#define DOT4(acc, Sa, Sb, Sc, Sd)                                  \
    acc += Sa.x*H0.x; acc += Sa.y*H0.y; acc += Sa.z*H0.z; acc += Sa.w*H0.w; \
    acc += Sb.x*H1.x; acc += Sb.y*H1.y; acc += Sb.z*H1.z; acc += Sb.w*H1.w; \
    acc += Sc.x*H2.x; acc += Sc.y*H2.y; acc += Sc.z*H2.z; acc += Sc.w*H2.w; \
    acc += Sd.x*H3.x; acc += Sd.y*H3.y; acc += Sd.z*H3.z; acc += Sd.w*H3.w

__global__ __launch_bounds__(768, 3) void lstm_fused(
    const int* __restrict__ x, const float* __restrict__ Gt,
    const float* __restrict__ w_hh0,
    const float* __restrict__ w_ih1, const float* __restrict__ w_hh1,
    const float* __restrict__ b_ih1, const float* __restrict__ b_hh1,
    const float* __restrict__ fc_w, const float* __restrict__ fc_b,
    float* __restrict__ out)
{
    const int tid = threadIdx.x;
    const int b   = blockIdx.x;
    const bool isA = tid < 256;
    const int lt  = isA ? tid : (tid - 256);
    const int q   = isA ? (lt >> 2) : (lt >> 3);
    const int j   = isA ? (lt & 3) : (lt & 7);
    const int gt  = j & 3;                 // gate this lane owns post-reduce

    __shared__ __align__(16) float h0b[2][HSZ];
    __shared__ __align__(16) float h1b[2][HSZ];
    __shared__ int xtok[TSZ];

    // Weight slice pointers (row of gate g = g*64+q -> +g*4096 elements).
    const float* pw1 = isA ? (w_hh0 + q * HSZ + 16 * j)
                           : (w_ih1 + q * HSZ + 8 * j);
    const float* pw2 = isA ? (w_hh0 + q * HSZ + 16 * j + 8)
                           : (w_hh1 + q * HSZ + 8 * j);

    float4 S00=LD4(pw1,0),     S01=LD4(pw1,4),     S02=LD4(pw2,0),     S03=LD4(pw2,4);
    float4 S10=LD4(pw1,4096),  S11=LD4(pw1,4100),  S12=LD4(pw2,4096),  S13=LD4(pw2,4100);
    float4 S20=LD4(pw1,8192),  S21=LD4(pw1,8196),  S22=LD4(pw2,8192),  S23=LD4(pw2,8196);
    float4 S30=LD4(pw1,12288), S31=LD4(pw1,12292), S32=LD4(pw2,12288), S33=LD4(pw2,12292);
    PIN4(S00); PIN4(S01); PIN4(S02); PIN4(S03);
    PIN4(S10); PIN4(S11); PIN4(S12); PIN4(S13);
    PIN4(S20); PIN4(S21); PIN4(S22); PIN4(S23);
    PIN4(S30); PIN4(S31); PIN4(S32); PIN4(S33);

    float addend_b = 0.f;                  // B: bias of its gate (invariant)
    if (!isA) addend_b = b_ih1[gt * HSZ + q] + b_hh1[gt * HSZ + q];
    const float mco = (gt == 2) ?  2.f : -1.f;   // unified activation consts
    const float Aco = (gt == 2) ?  1.f :  0.f;
    const float Bco = (gt == 2) ? -2.f :  1.f;

    if (tid < 128)      ((float*)h0b)[tid] = 0.f;        // both buffers
    else if (tid < 256) ((float*)h1b)[tid - 128] = 0.f;
    if (tid < TSZ) xtok[tid] = x[b * TSZ + tid];
    __syncthreads();

    float c = 0.f;
    float xg_cur = 0.f;
    if (isA) xg_cur = Gt[(size_t)xtok[0] * GSZ + 4 * q + j];

    #pragma unroll 1
    for (int k = 0; k <= TSZ; ++k) {
        // A: prefetch next token's gate scalar (survives the lgkm barrier).
        float xg_nxt = 0.f;
        if (isA && k + 1 < TSZ)
            xg_nxt = Gt[(size_t)xtok[k + 1] * GSZ + 4 * q + j];

        const float4* h0v = (const float4*)h0b[(k ^ 1) & 1];  // h0(k-1)
        const float4* h1v = (const float4*)h1b[k & 1];        // h1(k-2)
        const float4* hA  = h0v + (isA ? 4 * j : 2 * j);
        const float4* hB  = isA ? (h0v + 4 * j + 2) : (h1v + 2 * j);
        float4 H0 = hA[0], H1 = hA[1], H2 = hB[0], H3 = hB[1];

        float d0 = 0.f, d1 = 0.f, d2 = 0.f, d3 = 0.f;
        DOT4(d0, S00, S01, S02, S03);
        DOT4(d1, S10, S11, S12, S13);
        DOT4(d2, S20, S21, S22, S23);
        DOT4(d3, S30, S31, S32, S33);

        if (!isA) {                        // fold the two octet halves
            d0 += __shfl_xor(d0, 4, 64); d1 += __shfl_xor(d1, 4, 64);
            d2 += __shfl_xor(d2, 4, 64); d3 += __shfl_xor(d3, 4, 64);
        }
        // Reduce-scatter within quad: lane j&3 ends with gate j&3's dot.
        const bool lo2 = (j & 2) == 0;
        float u  = lo2 ? d2 : d0, v = lo2 ? d3 : d1;
        float ru = __shfl_xor(u, 2, 64), rv = __shfl_xor(v, 2, 64);
        float aa = (lo2 ? d0 : d2) + ru;
        float bb = (lo2 ? d1 : d3) + rv;
        const bool lo1 = (j & 1) == 0;
        float ws = lo1 ? bb : aa;
        float rw = __shfl_xor(ws, 1, 64);
        float s  = (lo1 ? aa : bb) + rw;

        s += isA ? xg_cur : addend_b;
        // One activation per lane: sigmoid (i,f,o) or tanh (g).
        float e   = __expf(mco * s);
        float act = fmaf(Bco, fast_rcp(1.f + e), Aco);

        // Allgather the 4 acts back across the quad (3 shuffles).
        float o1 = __shfl_xor(act, 1, 64);
        float ge = lo1 ? act : o1;         // even gate of this pair (i or g)
        float go = lo1 ? o1 : act;         // odd  gate (f or o)
        float pe = __shfl_xor(ge, 2, 64), po = __shfl_xor(go, 2, 64);
        float iact = lo2 ? ge : pe;
        float fact = lo2 ? go : po;
        float gact = lo2 ? pe : ge;
        float oact = lo2 ? po : go;

        const bool active = isA ? (k < TSZ) : (k >= 1);
        if (active) {
            c = fact * c + iact * gact;
            float hn = oact * tanh_f(c);
            if (j == 0) {
                if (isA) h0b[k & 1][q] = hn;              // h0(k)
                else     h1b[(k ^ 1) & 1][q] = hn;        // h1(k-1)
            }
        }
        xg_cur = xg_nxt;
        sync_lds();                        // lgkm-only: vmem stays in flight
    }

    // FC head on h1(T-1) = h1b[1] (wave 0 only).
    if (tid < HSZ) {
        float v = fmaxf(h1b[1][tid], 0.f) * fc_w[tid];
        #pragma unroll
        for (int off = 32; off > 0; off >>= 1) v += __shfl_down(v, off, 64);
        if (tid == 0) out[b] = sigmoid_f(v + fc_b[0]);
    }
}

extern "C" void kernel_launch(void* const* d_in, const int* in_sizes, int n_in,
                              void* d_out, int out_size, void* d_ws, size_t ws_size,
                              hipStream_t stream) {
    const int*   x     = (const int*)  d_in[0];
    const float* emb   = (const float*)d_in[1];
    const float* w_ih0 = (const float*)d_in[2];
    const float* w_hh0 = (const float*)d_in[3];
    const float* b_ih0 = (const float*)d_in[4];
    const float* b_hh0 = (const float*)d_in[5];
    const float* w_ih1 = (const float*)d_in[6];
    const float* w_hh1 = (const float*)d_in[7];
    const float* b_ih1 = (const float*)d_in[8];
    const float* b_hh1 = (const float*)d_in[9];
    const float* fc_w  = (const float*)d_in[10];
    const float* fc_b  = (const float*)d_in[11];
    float* out = (float*)d_out;

    // Workspace: permuted G table [V, 4H] fp32 = 51.2 MB.
    float* Gt = (float*)d_ws;

    build_table<<<dim3((VSZ + 31) / 32), dim3(256), 0, stream>>>(
        emb, w_ih0, b_ih0, b_hh0, Gt);
    lstm_fused<<<dim3(BSZ), dim3(768), 0, stream>>>(
        x, Gt, w_hh0, w_ih1, w_hh1, b_ih1, b_hh1, fc_w, fc_b, out);
}

// Round 5
// 538.054 us; speedup vs baseline: 1.2779x; 1.2779x over previous
//
#include <hip/hip_runtime.h>

// Problem constants (fixed by the reference setup_inputs).
#define VSZ 50000   // vocab
#define ESZ 100     // embedding dim
#define HSZ 64      // hidden
#define GSZ 256     // 4*H (gate width, PyTorch order i,f,g,o)
#define BSZ 256     // batch
#define TSZ 512     // seq len

__device__ __forceinline__ float fast_rcp(float x) { return __builtin_amdgcn_rcpf(x); }
__device__ __forceinline__ float sigmoid_f(float x) { return fast_rcp(1.f + __expf(-x)); }
__device__ __forceinline__ float tanh_f(float x) {
    float e = __expf(2.f * x);
    return 1.f - 2.f * fast_rcp(e + 1.f);
}

// ---------------------------------------------------------------------------
// Kernel A: G[v, col] = sum_e emb[v,e]*w_ih0[row,e] + b_ih0[row] + b_hh0[row],
// PERMUTED col = 4*(row%64) + row/64 so the recurrent kernel's lane (q,j)
// reads its gate scalar at col 4q+j.
// emb rows come in on the SMEM pipe (readfirstlane -> s_load, measured fast
// in r3); FOUR independent row streams per iteration give the SMEM pipe
// memory-level parallelism to hide its ~200cy L2 latency (r3 used 2).
// ---------------------------------------------------------------------------
__global__ __launch_bounds__(256) void build_table(
    const float* __restrict__ emb, const float* __restrict__ w_ih0,
    const float* __restrict__ b_ih0, const float* __restrict__ b_hh0,
    float* __restrict__ Gt)
{
    const int g = threadIdx.x;            // PyTorch gate-row index 0..255
    const int row0 = blockIdx.x * 32;
    const int col = ((g & 63) << 2) + (g >> 6);   // permuted column

    float w[ESZ];
    #pragma unroll
    for (int e = 0; e < ESZ; e += 4) {
        float4 v = *(const float4*)(w_ih0 + g * ESZ + e);
        w[e] = v.x; w[e + 1] = v.y; w[e + 2] = v.z; w[e + 3] = v.w;
    }
    const float bias = b_ih0[g] + b_hh0[g];

    #pragma unroll 1
    for (int r = row0; r < row0 + 32 && r < VSZ; r += 4) {
        // VSZ % 4 == 0 and tiles are 32-aligned: quads never straddle the end.
        const int off0 = __builtin_amdgcn_readfirstlane(r * ESZ);
        const float* e0 = emb + off0;
        const float* e1 = e0 + ESZ;
        const float* e2 = e0 + 2 * ESZ;
        const float* e3 = e0 + 3 * ESZ;
        float a0 = bias, a1 = 0.f, a2 = 0.f, a3 = 0.f;
        float b0 = bias, b1 = 0.f, b2 = 0.f, b3 = 0.f;
        float c0 = bias, c1 = 0.f, c2 = 0.f, c3 = 0.f;
        float d0 = bias, d1 = 0.f, d2 = 0.f, d3 = 0.f;
        #pragma unroll
        for (int e = 0; e < ESZ; e += 4) {
            a0 += e0[e    ] * w[e    ]; a1 += e0[e + 1] * w[e + 1];
            a2 += e0[e + 2] * w[e + 2]; a3 += e0[e + 3] * w[e + 3];
            b0 += e1[e    ] * w[e    ]; b1 += e1[e + 1] * w[e + 1];
            b2 += e1[e + 2] * w[e + 2]; b3 += e1[e + 3] * w[e + 3];
            c0 += e2[e    ] * w[e    ]; c1 += e2[e + 1] * w[e + 1];
            c2 += e2[e + 2] * w[e + 2]; c3 += e2[e + 3] * w[e + 3];
            d0 += e3[e    ] * w[e    ]; d1 += e3[e + 1] * w[e + 1];
            d2 += e3[e + 2] * w[e + 2]; d3 += e3[e + 3] * w[e + 3];
        }
        Gt[(size_t)r       * GSZ + col] = (a0 + a1) + (a2 + a3);
        Gt[(size_t)(r + 1) * GSZ + col] = (b0 + b1) + (b2 + b3);
        Gt[(size_t)(r + 2) * GSZ + col] = (c0 + c1) + (c2 + c3);
        Gt[(size_t)(r + 3) * GSZ + col] = (d0 + d1) + (d2 + d3);
    }
}

// ---------------------------------------------------------------------------
// Kernel B: fused 2-layer LSTM + FC head, 1 block (768 thr) per batch row.
//
// Group A (tid<256): layer 0. unit q = tid>>2, slice j = tid&3 (16 h-vals).
// Group B (tid>=256): layer 1. lt=tid-256, q=lt>>3, j=lt&7 (8 h-vals), with
//   the H operand = h0-slice ++ h1-slice so the dot code is identical to A's.
// 64 weight floats/thread, loaded ONCE and pinned with asm VOLATILE
// (r4's non-volatile pins were sunk into the loop -> weights re-streamed
// from L2 every step, VGPR_Count=52; volatile asm cannot be sunk/cloned, so
// the loop must use the register results). No per-iteration pins (r3's
// AGPR ping-pong bug). __launch_bounds__(768,2): VGPR cap 256 removes any
// pressure excuse to spill; occupancy is 1 block/CU regardless.
//
// Per step: 64 FMA -> reduce-scatter -> ONE activation per lane ->
// 3-shuffle allgather -> replicated c,h update, lane j==0 publishes h.
// A computes layer-0 step k while B computes layer-1 step k-1; ONE lgkm-only
// barrier per step (Gt prefetch stays in flight across it).
// ---------------------------------------------------------------------------
__device__ __forceinline__ void sync_lds() {
    asm volatile("s_waitcnt lgkmcnt(0)\n\ts_barrier" ::: "memory");
}

#define LD4(ptr, off) (*(const float4*)((ptr) + (off)))
#define PIN4(v) asm volatile("" : "+v"(v.x), "+v"(v.y), "+v"(v.z), "+v"(v.w))
#define DOT4(acc, Sa, Sb, Sc, Sd)                                  \
    acc += Sa.x*H0.x; acc += Sa.y*H0.y; acc += Sa.z*H0.z; acc += Sa.w*H0.w; \
    acc += Sb.x*H1.x; acc += Sb.y*H1.y; acc += Sb.z*H1.z; acc += Sb.w*H1.w; \
    acc += Sc.x*H2.x; acc += Sc.y*H2.y; acc += Sc.z*H2.z; acc += Sc.w*H2.w; \
    acc += Sd.x*H3.x; acc += Sd.y*H3.y; acc += Sd.z*H3.z; acc += Sd.w*H3.w

__global__ __launch_bounds__(768, 2) void lstm_fused(
    const int* __restrict__ x, const float* __restrict__ Gt,
    const float* __restrict__ w_hh0,
    const float* __restrict__ w_ih1, const float* __restrict__ w_hh1,
    const float* __restrict__ b_ih1, const float* __restrict__ b_hh1,
    const float* __restrict__ fc_w, const float* __restrict__ fc_b,
    float* __restrict__ out)
{
    const int tid = threadIdx.x;
    const int b   = blockIdx.x;
    const bool isA = tid < 256;
    const int lt  = isA ? tid : (tid - 256);
    const int q   = isA ? (lt >> 2) : (lt >> 3);
    const int j   = isA ? (lt & 3) : (lt & 7);
    const int gt  = j & 3;                 // gate this lane owns post-reduce

    __shared__ __align__(16) float h0b[2][HSZ];
    __shared__ __align__(16) float h1b[2][HSZ];
    __shared__ int xtok[TSZ];

    // Weight slice pointers (row of gate g = g*64+q -> +g*4096 elements).
    const float* pw1 = isA ? (w_hh0 + q * HSZ + 16 * j)
                           : (w_ih1 + q * HSZ + 8 * j);
    const float* pw2 = isA ? (w_hh0 + q * HSZ + 16 * j + 8)
                           : (w_hh1 + q * HSZ + 8 * j);

    float4 S00=LD4(pw1,0),     S01=LD4(pw1,4),     S02=LD4(pw2,0),     S03=LD4(pw2,4);
    float4 S10=LD4(pw1,4096),  S11=LD4(pw1,4100),  S12=LD4(pw2,4096),  S13=LD4(pw2,4100);
    float4 S20=LD4(pw1,8192),  S21=LD4(pw1,8196),  S22=LD4(pw2,8192),  S23=LD4(pw2,8196);
    float4 S30=LD4(pw1,12288), S31=LD4(pw1,12292), S32=LD4(pw2,12288), S33=LD4(pw2,12292);
    // Volatile, ONE-TIME register pins: cannot be sunk into the loop or
    // rematerialized; the values below are un-recomputable asm results.
    PIN4(S00); PIN4(S01); PIN4(S02); PIN4(S03);
    PIN4(S10); PIN4(S11); PIN4(S12); PIN4(S13);
    PIN4(S20); PIN4(S21); PIN4(S22); PIN4(S23);
    PIN4(S30); PIN4(S31); PIN4(S32); PIN4(S33);

    float addend_b = 0.f;                  // B: bias of its gate (invariant)
    if (!isA) addend_b = b_ih1[gt * HSZ + q] + b_hh1[gt * HSZ + q];
    const float mco = (gt == 2) ?  2.f : -1.f;   // unified activation consts
    const float Aco = (gt == 2) ?  1.f :  0.f;
    const float Bco = (gt == 2) ? -2.f :  1.f;

    if (tid < 128)      ((float*)h0b)[tid] = 0.f;        // both buffers
    else if (tid < 256) ((float*)h1b)[tid - 128] = 0.f;
    if (tid < TSZ) xtok[tid] = x[b * TSZ + tid];
    __syncthreads();

    float c = 0.f;
    float xg_cur = 0.f;
    if (isA) xg_cur = Gt[(size_t)xtok[0] * GSZ + 4 * q + j];

    #pragma unroll 1
    for (int k = 0; k <= TSZ; ++k) {
        // A: prefetch next token's gate scalar (survives the lgkm barrier).
        float xg_nxt = 0.f;
        if (isA && k + 1 < TSZ)
            xg_nxt = Gt[(size_t)xtok[k + 1] * GSZ + 4 * q + j];

        const float4* h0v = (const float4*)h0b[(k ^ 1) & 1];  // h0(k-1)
        const float4* h1v = (const float4*)h1b[k & 1];        // h1(k-2)
        const float4* hA  = h0v + (isA ? 4 * j : 2 * j);
        const float4* hB  = isA ? (h0v + 4 * j + 2) : (h1v + 2 * j);
        float4 H0 = hA[0], H1 = hA[1], H2 = hB[0], H3 = hB[1];

        float d0 = 0.f, d1 = 0.f, d2 = 0.f, d3 = 0.f;
        DOT4(d0, S00, S01, S02, S03);
        DOT4(d1, S10, S11, S12, S13);
        DOT4(d2, S20, S21, S22, S23);
        DOT4(d3, S30, S31, S32, S33);

        if (!isA) {                        // fold the two octet halves
            d0 += __shfl_xor(d0, 4, 64); d1 += __shfl_xor(d1, 4, 64);
            d2 += __shfl_xor(d2, 4, 64); d3 += __shfl_xor(d3, 4, 64);
        }
        // Reduce-scatter within quad: lane j&3 ends with gate j&3's dot.
        const bool lo2 = (j & 2) == 0;
        float u  = lo2 ? d2 : d0, v = lo2 ? d3 : d1;
        float ru = __shfl_xor(u, 2, 64), rv = __shfl_xor(v, 2, 64);
        float aa = (lo2 ? d0 : d2) + ru;
        float bb = (lo2 ? d1 : d3) + rv;
        const bool lo1 = (j & 1) == 0;
        float ws = lo1 ? bb : aa;
        float rw = __shfl_xor(ws, 1, 64);
        float s  = (lo1 ? aa : bb) + rw;

        s += isA ? xg_cur : addend_b;
        // One activation per lane: sigmoid (i,f,o) or tanh (g).
        float e   = __expf(mco * s);
        float act = fmaf(Bco, fast_rcp(1.f + e), Aco);

        // Allgather the 4 acts back across the quad (3 shuffles).
        float o1 = __shfl_xor(act, 1, 64);
        float ge = lo1 ? act : o1;         // even gate of this pair (i or g)
        float go = lo1 ? o1 : act;         // odd  gate (f or o)
        float pe = __shfl_xor(ge, 2, 64), po = __shfl_xor(go, 2, 64);
        float iact = lo2 ? ge : pe;
        float fact = lo2 ? go : po;
        float gact = lo2 ? pe : ge;
        float oact = lo2 ? po : go;

        const bool active = isA ? (k < TSZ) : (k >= 1);
        if (active) {
            c = fact * c + iact * gact;
            float hn = oact * tanh_f(c);
            if (j == 0) {
                if (isA) h0b[k & 1][q] = hn;              // h0(k)
                else     h1b[(k ^ 1) & 1][q] = hn;        // h1(k-1)
            }
        }
        xg_cur = xg_nxt;
        sync_lds();                        // lgkm-only: vmem stays in flight
    }

    // FC head on h1(T-1) = h1b[1] (wave 0 only).
    if (tid < HSZ) {
        float v = fmaxf(h1b[1][tid], 0.f) * fc_w[tid];
        #pragma unroll
        for (int off = 32; off > 0; off >>= 1) v += __shfl_down(v, off, 64);
        if (tid == 0) out[b] = sigmoid_f(v + fc_b[0]);
    }
}

extern "C" void kernel_launch(void* const* d_in, const int* in_sizes, int n_in,
                              void* d_out, int out_size, void* d_ws, size_t ws_size,
                              hipStream_t stream) {
    const int*   x     = (const int*)  d_in[0];
    const float* emb   = (const float*)d_in[1];
    const float* w_ih0 = (const float*)d_in[2];
    const float* w_hh0 = (const float*)d_in[3];
    const float* b_ih0 = (const float*)d_in[4];
    const float* b_hh0 = (const float*)d_in[5];
    const float* w_ih1 = (const float*)d_in[6];
    const float* w_hh1 = (const float*)d_in[7];
    const float* b_ih1 = (const float*)d_in[8];
    const float* b_hh1 = (const float*)d_in[9];
    const float* fc_w  = (const float*)d_in[10];
    const float* fc_b  = (const float*)d_in[11];
    float* out = (float*)d_out;

    // Workspace: permuted G table [V, 4H] fp32 = 51.2 MB.
    float* Gt = (float*)d_ws;

    build_table<<<dim3((VSZ + 31) / 32), dim3(256), 0, stream>>>(
        emb, w_ih0, b_ih0, b_hh0, Gt);
    lstm_fused<<<dim3(BSZ), dim3(768), 0, stream>>>(
        x, Gt, w_hh0, w_ih1, w_hh1, b_ih1, b_hh1, fc_w, fc_b, out);
}